// Round 3
// baseline (897.990 us; speedup 1.0000x reference)
//
#include <hip/hip_runtime.h>
#include <hip/hip_fp16.h>

typedef _Float16 f16;
typedef _Float16 f16x8 __attribute__((ext_vector_type(8)));
typedef _Float16 f16x4 __attribute__((ext_vector_type(4)));
typedef float f32x4 __attribute__((ext_vector_type(4)));

#define LN_EPS 1e-5f

typedef __attribute__((address_space(1))) unsigned int as1_u32;
typedef __attribute__((address_space(3))) unsigned int as3_u32;

__device__ __forceinline__ void gload_lds16(const void* g, void* l) {
    __builtin_amdgcn_global_load_lds((as1_u32*)g, (as3_u32*)l, 16, 0, 0);
}

__device__ __forceinline__ f32x4 mfma16(f16x8 a, f16x8 b, f32x4 c) {
    return __builtin_amdgcn_mfma_f32_16x16x32_f16(a, b, c, 0, 0, 0);
}

// ---------------- conversion: input + query f32 -> f16 in one launch ----------------

__global__ void k_cvt_dual(const float4* __restrict__ in0, const float4* __restrict__ in1,
                           f16x4* __restrict__ out0, f16x4* __restrict__ out1,
                           int nsplit, int ntot) {
    int i = blockIdx.x * blockDim.x + threadIdx.x;
    int st = gridDim.x * blockDim.x;
    for (; i < ntot; i += st) {
        const bool lo = i < nsplit;
        const float4 v = lo ? in0[i] : in1[i - nsplit];
        f16x4 o;
        o.x = (f16)v.x; o.y = (f16)v.y; o.z = (f16)v.z; o.w = (f16)v.w;
        if (lo) out0[i] = o; else out1[i - nsplit] = o;
    }
}

// all 4 weight transposes ([1024][Nw] f32 -> [Nw][1024] f16) in one launch
__global__ __launch_bounds__(256) void k_transpose_all(const float* __restrict__ kw,
                                                       const float* __restrict__ vw,
                                                       const float* __restrict__ qw,
                                                       const float* __restrict__ pw,
                                                       f16* __restrict__ BkvT,
                                                       f16* __restrict__ qwT,
                                                       f16* __restrict__ pwT) {
    __shared__ float t[32][33];
    const int x = blockIdx.x;
    const float* W; f16* WT; int Nw, nt0;
    if (x < 16)      { W = kw; WT = BkvT;                     Nw = 512;  nt0 = x; }
    else if (x < 48) { W = vw; WT = BkvT + (size_t)512 * 1024; Nw = 1024; nt0 = x - 16; }
    else if (x < 64) { W = qw; WT = qwT;                      Nw = 512;  nt0 = x - 48; }
    else             { W = pw; WT = pwT;                      Nw = 1024; nt0 = x - 64; }
    const int n0 = nt0 * 32, k0 = blockIdx.y * 32;
    const int tx = threadIdx.x & 31, ty = threadIdx.x >> 5;
#pragma unroll
    for (int i = 0; i < 32; i += 8)
        t[ty + i][tx] = W[(size_t)(k0 + ty + i) * Nw + n0 + tx];
    __syncthreads();
#pragma unroll
    for (int i = 0; i < 32; i += 8)
        WT[(size_t)(n0 + ty + i) * 1024 + k0 + tx] = (f16)t[tx][ty + i];
}

// ---------------- big K/V GEMM: Ckv[65536][1536] = A16 @ BkvT^T + bias; stats fused ----
// 256x256 tile, 8 waves (2x4), 32 phases (16 K-tiles x 2 k-halves), 4-slot LDS ring
// (32KB = A-half 16KB + B-half 16KB), counted vmcnt(8), per-phase barriers, setprio.
// k-chunk XOR swizzle (both sides). Grid 1536 = 6 x 256, XCD-bijective swizzle.

__global__ __launch_bounds__(512, 2) void k_gemm256(const f16* __restrict__ A,
                                                    const f16* __restrict__ Bt,
                                                    f16* __restrict__ C,
                                                    const float* __restrict__ bias1,
                                                    const float* __restrict__ bias2,
                                                    float* __restrict__ stats) {
    extern __shared__ char lds[];
    const int tid = threadIdx.x, lane = tid & 63, w = tid >> 6;
    const int wr = w >> 2, wc = w & 3;
    const int lane15 = lane & 15, l4 = lane >> 4;

    const int swz = ((int)blockIdx.x & 7) * 192 + ((int)blockIdx.x >> 3);
    const int bx = swz % 6, by = swz / 6;
    const size_t m0 = (size_t)by * 256, n0g = (size_t)bx * 256;

    // staging geometry: wave w stages rows [w*32, w*32+32) of A-half and B-half.
    // issue i covers 16 rows; lane L -> row +(L>>2), LDS 16B-chunk (L&3), global
    // chunk (L&3)^((L>>3)&3)  [LDS pos p of row r holds global chunk p^((r>>1)&3)]
    const int lrow4 = lane >> 2;
    const int lchunk = (lane & 3) ^ ((lane >> 3) & 3);
    const f16* gA = A + (m0 + w * 32 + lrow4) * 1024 + lchunk * 8;
    const f16* gB = Bt + (n0g + w * 32 + lrow4) * 1024 + lchunk * 8;
    const int dstA = w * 2048;  // byte offset of wave's 32-row block in a 16KB half

    // fragment-read offsets (within slot): row*64B + swizzled 16B chunk
    const int csw = l4 ^ ((lane15 >> 1) & 3);
    const int ofsA = (wr * 128 + lane15) * 64 + csw * 16;
    const int ofsB = 16384 + (wc * 64 + lane15) * 64 + csw * 16;

    f32x4 acc[8][4] = {};

#define STAGE_C(content)                                                         \
    {                                                                            \
        const int _sl = (content) & 3;                                           \
        const int _ko = ((content) >> 1) * 64 + ((content) & 1) * 32;            \
        char* _b = lds + _sl * 32768;                                            \
        gload_lds16(gA + _ko, _b + dstA);                                        \
        gload_lds16(gA + _ko + 16 * 1024, _b + dstA + 1024);                     \
        gload_lds16(gB + _ko, _b + 16384 + dstA);                                \
        gload_lds16(gB + _ko + 16 * 1024, _b + 16384 + dstA + 1024);             \
    }

#define PHASE(slotc, stage_content, vmN)                                         \
    {                                                                            \
        const char* sb = lds + (slotc) * 32768;                                  \
        f16x8 af[8], bf[4];                                                      \
        _Pragma("unroll") for (int m = 0; m < 8; m++)                            \
            af[m] = *(const f16x8*)(sb + ofsA + m * 1024);                       \
        _Pragma("unroll") for (int n = 0; n < 4; n++)                            \
            bf[n] = *(const f16x8*)(sb + ofsB + n * 1024);                       \
        if ((stage_content) >= 0) STAGE_C(stage_content)                         \
        if ((vmN) == 8) asm volatile("s_waitcnt vmcnt(8)" ::: "memory");         \
        else if ((vmN) == 4) asm volatile("s_waitcnt vmcnt(4)" ::: "memory");    \
        else if ((vmN) == 0) asm volatile("s_waitcnt vmcnt(0)" ::: "memory");    \
        __builtin_amdgcn_s_barrier();                                            \
        __builtin_amdgcn_s_setprio(1);                                           \
        _Pragma("unroll") for (int m = 0; m < 8; m++)                            \
            _Pragma("unroll") for (int n = 0; n < 4; n++)                        \
                acc[m][n] = mfma16(af[m], bf[n], acc[m][n]);                     \
        __builtin_amdgcn_s_setprio(0);                                           \
        __builtin_amdgcn_s_barrier();                                            \
    }

    // prologue: contents 0,1,2 -> slots 0,1,2; retire content 0
    STAGE_C(0) STAGE_C(1) STAGE_C(2)
    asm volatile("s_waitcnt vmcnt(8)" ::: "memory");
    __builtin_amdgcn_s_barrier();

#pragma unroll 4
    for (int g = 0; g < 28; ++g) PHASE(g & 3, g + 3, 8)
    PHASE(0, 31, 8)
    PHASE(1, -1, 4)
    PHASE(2, -1, 0)
    PHASE(3, -1, -1)
#undef PHASE
#undef STAGE_C

    // ---- epilogue 1: C tile (f16 + bias) via LDS for coalesced stores ----
    {
        f16* Ct = (f16*)lds;
#pragma unroll
        for (int m = 0; m < 8; m++)
#pragma unroll
            for (int n = 0; n < 4; n++) {
                const int row = wr * 128 + m * 16 + l4 * 4;
                const int col = wc * 64 + n * 16 + lane15;
                const int cg = (int)n0g + col;
                const float bv = (cg < 512) ? bias1[cg] : bias2[cg - 512];
#pragma unroll
                for (int j = 0; j < 4; j++)
                    Ct[(row + j) * 256 + col] = (f16)(acc[m][n][j] + bv);
            }
        __syncthreads();
#pragma unroll
        for (int it = 0; it < 16; it++) {
            const int flat = it * 512 + tid;
            const int row = flat >> 5;
            const int ce = (flat & 31) * 8;
            *(f16x8*)(C + (m0 + row) * 1536 + n0g + ce) = *(const f16x8*)(Ct + row * 256 + ce);
        }
        __syncthreads();
    }
    // ---- epilogue 2: fused LN row partial sums -> global atomics ----
    {
        float* SP = (float*)lds;  // [256 rows][4 wc][2 comp]
        const int part = (n0g >= 512) ? 1 : 0;
#pragma unroll
        for (int half = 0; half < 2; half++) {
            float s1[4][4], s2[4][4];
#pragma unroll
            for (int m = 0; m < 4; m++)
#pragma unroll
                for (int j = 0; j < 4; j++) { s1[m][j] = 0.f; s2[m][j] = 0.f; }
#pragma unroll
            for (int m = 0; m < 4; m++) {
                const int mm = half * 4 + m;
#pragma unroll
                for (int n = 0; n < 4; n++) {
                    const int cg = (int)n0g + wc * 64 + n * 16 + lane15;
                    const float bv = (cg < 512) ? bias1[cg] : bias2[cg - 512];
#pragma unroll
                    for (int j = 0; j < 4; j++) {
                        const float v = acc[mm][n][j] + bv;
                        s1[m][j] += v;
                        s2[m][j] += v * v;
                    }
                }
#pragma unroll
                for (int j = 0; j < 4; j++) {
#pragma unroll
                    for (int o = 1; o < 16; o <<= 1) {
                        s1[m][j] += __shfl_xor(s1[m][j], o);
                        s2[m][j] += __shfl_xor(s2[m][j], o);
                    }
                }
            }
            if (lane15 == 0) {
#pragma unroll
                for (int m = 0; m < 4; m++)
#pragma unroll
                    for (int j = 0; j < 4; j++) {
                        const int row = wr * 128 + (half * 4 + m) * 16 + l4 * 4 + j;
                        SP[row * 8 + wc * 2 + 0] = s1[m][j];
                        SP[row * 8 + wc * 2 + 1] = s2[m][j];
                    }
            }
        }
        __syncthreads();
        {
            const int row = tid >> 1, comp = tid & 1;
            const float v = SP[row * 8 + 0 + comp] + SP[row * 8 + 2 + comp] +
                            SP[row * 8 + 4 + comp] + SP[row * 8 + 6 + comp];
            atomicAdd(stats + (m0 + row) * 4 + part * 2 + comp, v);
        }
    }
}

// finalize (sum,sumsq) -> (mu, rstd) in place; stats[row] = {k: s,s2, v: s,s2}
__global__ void k_statsfin(float4* __restrict__ stats) {
    const int i = blockIdx.x * 256 + threadIdx.x;
    const float4 s = stats[i];
    const float muk = s.x * (1.f / 512.f);
    const float vk = s.y * (1.f / 512.f) - muk * muk;
    const float muv = s.z * (1.f / 1024.f);
    const float vv = s.w * (1.f / 1024.f) - muv * muv;
    stats[i] = make_float4(muk, rsqrtf(vk + LN_EPS), muv, rsqrtf(vv + LN_EPS));
}

// ---------------- small GEMM (q / proj): 128x128 tile, m97-style ----------------

template <bool OUTF32>
__global__ __launch_bounds__(256, 2) void k_gemm(const f16* __restrict__ A,
                                                 const f16* __restrict__ Bt,
                                                 void* __restrict__ Cout, int Ncols, int Kd,
                                                 const float* __restrict__ bias1,
                                                 const float* __restrict__ bias2, int bsplit) {
    __shared__ f16 smem[16384];
    const int tid = threadIdx.x, lane = tid & 63, wave = tid >> 6;
    const int m0 = blockIdx.y * 128, n0 = blockIdx.x * 128;
    const size_t ldb = (size_t)Kd * 2;
    f32x4 acc[4][4] = {};

    const int rA = wave * 8 + (lane >> 3);
    const int slot = (lane & 7) * 16;
    const char* Ab = (const char*)A + (size_t)(m0 + rA) * ldb + slot;
    const char* Bb = (const char*)Bt + (size_t)(n0 + rA) * ldb + slot;
    char* lA = (char*)smem + wave * 1024;
    char* lB = (char*)smem + 16384 + wave * 1024;

    const int wm = (wave & 1) * 64, wn = (wave >> 1) * 64;

    for (int k0 = 0; k0 < Kd; k0 += 64) {
#pragma unroll
        for (int i = 0; i < 4; i++) {
            gload_lds16(Ab + (size_t)k0 * 2 + (size_t)i * 32 * ldb, lA + i * 4096);
            gload_lds16(Bb + (size_t)k0 * 2 + (size_t)i * 32 * ldb, lB + i * 4096);
        }
        __syncthreads();
#pragma unroll
        for (int kk = 0; kk < 64; kk += 32) {
            const int kb = (kk + (lane >> 4) * 8) * 2;
            f16x8 af[4], bf[4];
#pragma unroll
            for (int mi = 0; mi < 4; mi++)
                af[mi] = *(const f16x8*)((const char*)smem + (wm + mi * 16 + (lane & 15)) * 128 + kb);
#pragma unroll
            for (int ni = 0; ni < 4; ni++)
                bf[ni] = *(const f16x8*)((const char*)smem + 16384 + (wn + ni * 16 + (lane & 15)) * 128 + kb);
#pragma unroll
            for (int mi = 0; mi < 4; mi++)
#pragma unroll
                for (int ni = 0; ni < 4; ni++)
                    acc[mi][ni] = mfma16(af[mi], bf[ni], acc[mi][ni]);
        }
        __syncthreads();
    }

    if (!OUTF32) {
        f16* Ct = smem;
#pragma unroll
        for (int mi = 0; mi < 4; mi++) {
#pragma unroll
            for (int ni = 0; ni < 4; ni++) {
                const int r = wm + mi * 16 + (lane >> 4) * 4;
                const int c = wn + ni * 16 + (lane & 15);
                const int cg = n0 + c;
                const float bv = (cg < bsplit) ? bias1[cg] : bias2[cg - bsplit];
#pragma unroll
                for (int j = 0; j < 4; j++) Ct[(r + j) * 128 + c] = (f16)(acc[mi][ni][j] + bv);
            }
        }
        __syncthreads();
        f16* Cg = (f16*)Cout;
        const int r = tid >> 1, half = tid & 1;
        const f16* src = Ct + r * 128 + half * 64;
        f16* dst = Cg + (size_t)(m0 + r) * Ncols + n0 + half * 64;
#pragma unroll
        for (int i = 0; i < 8; i++) *(f16x8*)(dst + i * 8) = *(const f16x8*)(src + i * 8);
    } else {
        float* Cg = (float*)Cout;
#pragma unroll
        for (int mi = 0; mi < 4; mi++) {
#pragma unroll
            for (int ni = 0; ni < 4; ni++) {
                const int r = wm + mi * 16 + (lane >> 4) * 4;
                const int c = wn + ni * 16 + (lane & 15);
                const int cg = n0 + c;
                const float bv = (cg < bsplit) ? bias1[cg] : bias2[cg - bsplit];
#pragma unroll
                for (int j = 0; j < 4; j++)
                    Cg[(size_t)(m0 + r + j) * Ncols + cg] = acc[mi][ni][j] + bv;
            }
        }
    }
}

// ---------------- column softmax stats (k^T over tokens), slab = 64 rows ----------------

__global__ __launch_bounds__(256) void k_colstats1(const f16* __restrict__ Ckv,
                                                   const float4* __restrict__ stats,
                                                   const float* __restrict__ kg,
                                                   const float* __restrict__ kb,
                                                   float* __restrict__ pm, float* __restrict__ ps) {
    const int b = blockIdx.y, slab = blockIdx.x, t = threadIdx.x;
    const int c0 = t * 2;
    const float g0 = kg[c0], g1 = kg[c0 + 1], e0 = kb[c0], e1 = kb[c0 + 1];
    const size_t r0 = (size_t)b * 8192 + slab * 64;
    float m0 = -1e30f, m1 = -1e30f;
    for (int r = 0; r < 64; r++) {
        const float4 st = stats[r0 + r];
        union { unsigned u; f16 h[2]; } w;
        w.u = *(const unsigned*)(Ckv + (r0 + r) * 1536 + c0);
        const float z0 = ((float)w.h[0] - st.x) * st.y * g0 + e0;
        const float z1 = ((float)w.h[1] - st.x) * st.y * g1 + e1;
        m0 = fmaxf(m0, z0);
        m1 = fmaxf(m1, z1);
    }
    float s0 = 0.f, s1 = 0.f;
    for (int r = 0; r < 64; r++) {
        const float4 st = stats[r0 + r];
        union { unsigned u; f16 h[2]; } w;
        w.u = *(const unsigned*)(Ckv + (r0 + r) * 1536 + c0);
        const float z0 = ((float)w.h[0] - st.x) * st.y * g0 + e0;
        const float z1 = ((float)w.h[1] - st.x) * st.y * g1 + e1;
        s0 += __expf(z0 - m0);
        s1 += __expf(z1 - m1);
    }
    const int o = (b * 128 + slab) * 512 + c0;
    pm[o] = m0; pm[o + 1] = m1;
    ps[o] = s0; ps[o + 1] = s1;
}

__global__ void k_colstats2(const float* __restrict__ pm, const float* __restrict__ ps,
                            float* __restrict__ Mx, float* __restrict__ invZ) {
    const int idx = blockIdx.x * 256 + threadIdx.x;  // 0..4095
    const int b = idx >> 9, c = idx & 511;
    float M = -1e30f;
    for (int s = 0; s < 128; s++) M = fmaxf(M, pm[(b * 128 + s) * 512 + c]);
    float S = 0.f;
    for (int s = 0; s < 128; s++) S += ps[(b * 128 + s) * 512 + c] * __expf(pm[(b * 128 + s) * 512 + c] - M);
    Mx[idx] = M;
    invZ[idx] = 1.0f / S;
}

// ---------------- kv einsum partials over token splits ----------------

__global__ __launch_bounds__(256, 2) void k_kv(const f16* __restrict__ Ckv,
                                               const float4* __restrict__ stats,
                                               const float* __restrict__ kg,
                                               const float* __restrict__ kbe,
                                               const float* __restrict__ vg,
                                               const float* __restrict__ vbe,
                                               const float* __restrict__ Mx,
                                               float* __restrict__ kvpart) {
    __shared__ f16 As[64 * 64];
    __shared__ f16 Vs[128 * 64];
    __shared__ float cgk[64], cbk[64], cmx[64], cgv[128], cbv[128];
    const int split = blockIdx.x, bh = blockIdx.y;
    const int b = bh >> 3, h = bh & 7;
    const int tid = threadIdx.x, lane = tid & 63, wave = tid >> 6;
    if (tid < 64) {
        cgk[tid] = kg[h * 64 + tid];
        cbk[tid] = kbe[h * 64 + tid];
        cmx[tid] = Mx[b * 512 + h * 64 + tid];
    }
    if (tid < 128) {
        cgv[tid] = vg[h * 128 + tid];
        cbv[tid] = vbe[h * 128 + tid];
    }
    __syncthreads();
    f32x4 acc[8] = {};
    const size_t base = (size_t)b * 8192 + split * 1024;
    for (int t0 = 0; t0 < 1024; t0 += 64) {
        {
            const int g = tid & 7, p = tid >> 3;
            const size_t row = base + t0 + 2 * p;
            const f16x8 x0 = *(const f16x8*)(Ckv + row * 1536 + h * 64 + g * 8);
            const f16x8 x1 = *(const f16x8*)(Ckv + (row + 1) * 1536 + h * 64 + g * 8);
            const float4 s0 = stats[row], s1 = stats[row + 1];
#pragma unroll
            for (int j = 0; j < 8; j++) {
                const int c = g * 8 + j;
                const float z0 = ((float)x0[j] - s0.x) * s0.y * cgk[c] + cbk[c] - cmx[c];
                const float z1 = ((float)x1[j] - s1.x) * s1.y * cgk[c] + cbk[c] - cmx[c];
                union { unsigned u; f16 h2[2]; } pk;
                pk.h2[0] = (f16)__expf(z0);
                pk.h2[1] = (f16)__expf(z1);
                *(unsigned*)((char*)As + c * 128 + 4 * p) = pk.u;
            }
        }
#pragma unroll
        for (int sub = 0; sub < 2; sub++) {
            const int idx = tid + sub * 256;
            const int g = idx & 15, p = idx >> 4;
            const size_t row = base + t0 + 2 * p;
            const f16x8 x0 = *(const f16x8*)(Ckv + row * 1536 + 512 + h * 128 + g * 8);
            const f16x8 x1 = *(const f16x8*)(Ckv + (row + 1) * 1536 + 512 + h * 128 + g * 8);
            const float4 s0 = stats[row], s1 = stats[row + 1];
#pragma unroll
            for (int j = 0; j < 8; j++) {
                const int d = g * 8 + j;
                const float z0 = ((float)x0[j] - s0.z) * s0.w * cgv[d] + cbv[d];
                const float z1 = ((float)x1[j] - s1.z) * s1.w * cgv[d] + cbv[d];
                union { unsigned u; f16 h2[2]; } pk;
                pk.h2[0] = (f16)z0;
                pk.h2[1] = (f16)z1;
                *(unsigned*)((char*)Vs + d * 128 + 4 * p) = pk.u;
            }
        }
        __syncthreads();
#pragma unroll
        for (int kk = 0; kk < 64; kk += 32) {
            const int kb2 = (kk + (lane >> 4) * 8) * 2;
            const f16x8 af = *(const f16x8*)((const char*)As + (wave * 16 + (lane & 15)) * 128 + kb2);
#pragma unroll
            for (int ni = 0; ni < 8; ni++) {
                const f16x8 bf = *(const f16x8*)((const char*)Vs + (ni * 16 + (lane & 15)) * 128 + kb2);
                acc[ni] = mfma16(af, bf, acc[ni]);
            }
        }
        __syncthreads();
    }
    float* out = kvpart + ((size_t)split * 64 + bh) * 8192;
    const int l = wave * 16 + (lane >> 4) * 4;
#pragma unroll
    for (int ni = 0; ni < 8; ni++) {
        const int d = ni * 16 + (lane & 15);
#pragma unroll
        for (int j = 0; j < 4; j++) out[(l + j) * 128 + d] = acc[ni][j];
    }
}

__global__ void k_kvreduce(const float* __restrict__ kvpart, const float* __restrict__ invZ,
                           f16* __restrict__ kvT) {
    const int idx = blockIdx.x * 256 + threadIdx.x;
    const int d = idx & 127, l = (idx >> 7) & 63, bh = idx >> 13;
    const int b = bh >> 3, h = bh & 7;
    float s = 0.f;
#pragma unroll
    for (int sp = 0; sp < 8; sp++) s += kvpart[((size_t)sp * 64 + bh) * 8192 + l * 128 + d];
    s *= invZ[b * 512 + h * 64 + l];
    kvT[((size_t)bh * 128 + d) * 64 + l] = (f16)s;
}

// ---------------- q: LN + per-head softmax ----------------

__global__ __launch_bounds__(512) void k_qsm(const f16* __restrict__ qlin,
                                             const float* __restrict__ qg,
                                             const float* __restrict__ qbeta,
                                             f16* __restrict__ qsm) {
    const int row = blockIdx.x, t = threadIdx.x;
    const float x = (float)qlin[(size_t)row * 512 + t];
    float s = x, s2 = x * x;
#pragma unroll
    for (int off = 32; off; off >>= 1) {
        s += __shfl_xor(s, off);
        s2 += __shfl_xor(s2, off);
    }
    __shared__ float rs[16];
    const int wave = t >> 6, lane = t & 63;
    if (lane == 0) {
        rs[wave] = s;
        rs[8 + wave] = s2;
    }
    __syncthreads();
    float S = 0.f, S2 = 0.f;
#pragma unroll
    for (int w = 0; w < 8; w++) {
        S += rs[w];
        S2 += rs[8 + w];
    }
    const float mu = S * (1.0f / 512.0f);
    const float var = S2 * (1.0f / 512.0f) - mu * mu;
    const float z = (x - mu) * rsqrtf(var + LN_EPS) * qg[t] + qbeta[t];
    float m = z;
#pragma unroll
    for (int off = 32; off; off >>= 1) m = fmaxf(m, __shfl_xor(m, off));
    const float e = __expf(z - m);
    float se = e;
#pragma unroll
    for (int off = 32; off; off >>= 1) se += __shfl_xor(se, off);
    qsm[(size_t)row * 512 + t] = (f16)(e / se);
}

// ---------------- out_mid = qsm @ kvT ----------------

__global__ __launch_bounds__(256) void k_qkv(const f16* __restrict__ qsm,
                                             const f16* __restrict__ kvT,
                                             f16* __restrict__ omid) {
    const int ms = blockIdx.x, bh = blockIdx.y;
    const int b = bh >> 3, h = bh & 7;
    const int tid = threadIdx.x, lane = tid & 63, wave = tid >> 6;
    const int mr = ms * 64 + wave * 16;
    f32x4 acc[8] = {};
    const f16* Ab = qsm + (size_t)(b * 256 + mr + (lane & 15)) * 512 + h * 64;
    const f16* Bb = kvT + (size_t)bh * 8192;
#pragma unroll
    for (int kk = 0; kk < 64; kk += 32) {
        const int k = kk + (lane >> 4) * 8;
        const f16x8 af = *(const f16x8*)(Ab + k);
#pragma unroll
        for (int ni = 0; ni < 8; ni++) {
            const f16x8 bf = *(const f16x8*)(Bb + (ni * 16 + (lane & 15)) * 64 + k);
            acc[ni] = mfma16(af, bf, acc[ni]);
        }
    }
    const int r = b * 256 + mr + (lane >> 4) * 4;
#pragma unroll
    for (int ni = 0; ni < 8; ni++) {
        const int d = h * 128 + ni * 16 + (lane & 15);
#pragma unroll
        for (int j = 0; j < 4; j++) omid[(size_t)(r + j) * 1024 + d] = (f16)acc[ni][j];
    }
}

// ---------------- launch ----------------

extern "C" void kernel_launch(void* const* d_in, const int* in_sizes, int n_in,
                              void* d_out, int out_size, void* d_ws, size_t ws_size,
                              hipStream_t stream) {
    const float* input  = (const float*)d_in[0];
    const float* query  = (const float*)d_in[1];
    const float* q_w    = (const float*)d_in[2];
    const float* q_b    = (const float*)d_in[3];
    const float* q_g    = (const float*)d_in[4];
    const float* q_beta = (const float*)d_in[5];
    const float* k_w    = (const float*)d_in[6];
    const float* k_b    = (const float*)d_in[7];
    const float* k_g    = (const float*)d_in[8];
    const float* k_beta = (const float*)d_in[9];
    const float* v_w    = (const float*)d_in[10];
    const float* v_b    = (const float*)d_in[11];
    const float* v_g    = (const float*)d_in[12];
    const float* v_beta = (const float*)d_in[13];
    const float* proj_w = (const float*)d_in[14];
    const float* proj_b = (const float*)d_in[15];

    char* ws = (char*)d_ws;
    size_t off = 0;
    auto alloc = [&](size_t bytes) {
        char* p = ws + off;
        off += (bytes + 255) & ~(size_t)255;
        return p;
    };
    f16*   A16    = (f16*)alloc((size_t)67108864 * 2);
    f16*   Q16    = (f16*)alloc((size_t)2097152 * 2);
    f16*   BkvT   = (f16*)alloc((size_t)1536 * 1024 * 2);
    f16*   qwT    = (f16*)alloc((size_t)512 * 1024 * 2);
    f16*   pwT    = (f16*)alloc((size_t)1024 * 1024 * 2);
    f16*   Ckv    = (f16*)alloc((size_t)65536 * 1536 * 2);
    float* stats  = (float*)alloc((size_t)65536 * 16);
    float* pm     = (float*)alloc((size_t)8 * 128 * 512 * 4);
    float* ps     = (float*)alloc((size_t)8 * 128 * 512 * 4);
    float* Mx     = (float*)alloc((size_t)8 * 512 * 4);
    float* invZ   = (float*)alloc((size_t)8 * 512 * 4);
    f16*   qlin   = (f16*)alloc((size_t)2048 * 512 * 2);
    f16*   qsm    = (f16*)alloc((size_t)2048 * 512 * 2);
    float* kvpart = (float*)alloc((size_t)8 * 64 * 64 * 128 * 4);
    f16*   kvT    = (f16*)alloc((size_t)64 * 128 * 64 * 2);
    f16*   omid   = (f16*)alloc((size_t)2048 * 1024 * 2);
    (void)ws_size; (void)in_sizes; (void)n_in; (void)out_size;

    hipFuncSetAttribute(reinterpret_cast<const void*>(k_gemm256),
                        hipFuncAttributeMaxDynamicSharedMemorySize, 131072);

    // 0) zero the fused-stats accumulator
    hipMemsetAsync(stats, 0, (size_t)65536 * 16, stream);

    // 1) converts + weight transposes
    k_cvt_dual<<<2048, 256, 0, stream>>>((const float4*)input, (const float4*)query,
                                         (f16x4*)A16, (f16x4*)Q16, 16777216, 17301504);
    k_transpose_all<<<dim3(96, 32), 256, 0, stream>>>(k_w, v_w, q_w, proj_w, BkvT, qwT, pwT);

    // 2) fused K/V projection GEMM (ring-pipelined) + LN stats accumulation
    k_gemm256<<<1536, 512, 131072, stream>>>(A16, BkvT, Ckv, k_b, v_b, stats);
    k_statsfin<<<256, 256, 0, stream>>>((float4*)stats);

    // 3) column softmax stats for k^T
    k_colstats1<<<dim3(128, 8), 256, 0, stream>>>(Ckv, (const float4*)stats, k_g, k_beta, pm, ps);
    k_colstats2<<<16, 256, 0, stream>>>(pm, ps, Mx, invZ);

    // 4) kv einsum + reduce
    k_kv<<<dim3(8, 64), 256, 0, stream>>>(Ckv, (const float4*)stats, k_g, k_beta, v_g, v_beta, Mx, kvpart);
    k_kvreduce<<<2048, 256, 0, stream>>>(kvpart, invZ, kvT);

    // 5) q path
    k_gemm<false><<<dim3(4, 16), 256, 0, stream>>>(Q16, qwT, qlin, 512, 1024, q_b, q_b, 512);
    k_qsm<<<2048, 512, 0, stream>>>(qlin, q_g, q_beta, qsm);
    k_qkv<<<dim3(4, 64), 256, 0, stream>>>(qsm, kvT, omid);
    k_gemm<true><<<dim3(8, 16), 256, 0, stream>>>(omid, pwT, d_out, 1024, 1024, proj_b, proj_b, 2048);
}

// Round 4
// 880.040 us; speedup vs baseline: 1.0204x; 1.0204x over previous
//
#include <hip/hip_runtime.h>
#include <hip/hip_fp16.h>

typedef _Float16 f16;
typedef _Float16 f16x8 __attribute__((ext_vector_type(8)));
typedef _Float16 f16x4 __attribute__((ext_vector_type(4)));
typedef float f32x4 __attribute__((ext_vector_type(4)));

#define LN_EPS 1e-5f

typedef __attribute__((address_space(1))) unsigned int as1_u32;
typedef __attribute__((address_space(3))) unsigned int as3_u32;

__device__ __forceinline__ void gload_lds16(const void* g, void* l) {
    __builtin_amdgcn_global_load_lds((as1_u32*)g, (as3_u32*)l, 16, 0, 0);
}

__device__ __forceinline__ f32x4 mfma16(f16x8 a, f16x8 b, f32x4 c) {
    return __builtin_amdgcn_mfma_f32_16x16x32_f16(a, b, c, 0, 0, 0);
}

// ---------------- conversion: input + query f32 -> f16 in one launch ----------------

__global__ void k_cvt_dual(const float4* __restrict__ in0, const float4* __restrict__ in1,
                           f16x4* __restrict__ out0, f16x4* __restrict__ out1,
                           int nsplit, int ntot) {
    int i = blockIdx.x * blockDim.x + threadIdx.x;
    int st = gridDim.x * blockDim.x;
    for (; i < ntot; i += st) {
        const bool lo = i < nsplit;
        const float4 v = lo ? in0[i] : in1[i - nsplit];
        f16x4 o;
        o.x = (f16)v.x; o.y = (f16)v.y; o.z = (f16)v.z; o.w = (f16)v.w;
        if (lo) out0[i] = o; else out1[i - nsplit] = o;
    }
}

// all 4 weight transposes ([1024][Nw] f32 -> [Nw][1024] f16) in one launch
__global__ __launch_bounds__(256) void k_transpose_all(const float* __restrict__ kw,
                                                       const float* __restrict__ vw,
                                                       const float* __restrict__ qw,
                                                       const float* __restrict__ pw,
                                                       f16* __restrict__ BkvT,
                                                       f16* __restrict__ qwT,
                                                       f16* __restrict__ pwT) {
    __shared__ float t[32][33];
    const int x = blockIdx.x;
    const float* W; f16* WT; int Nw, nt0;
    if (x < 16)      { W = kw; WT = BkvT;                     Nw = 512;  nt0 = x; }
    else if (x < 48) { W = vw; WT = BkvT + (size_t)512 * 1024; Nw = 1024; nt0 = x - 16; }
    else if (x < 64) { W = qw; WT = qwT;                      Nw = 512;  nt0 = x - 48; }
    else             { W = pw; WT = pwT;                      Nw = 1024; nt0 = x - 64; }
    const int n0 = nt0 * 32, k0 = blockIdx.y * 32;
    const int tx = threadIdx.x & 31, ty = threadIdx.x >> 5;
#pragma unroll
    for (int i = 0; i < 32; i += 8)
        t[ty + i][tx] = W[(size_t)(k0 + ty + i) * Nw + n0 + tx];
    __syncthreads();
#pragma unroll
    for (int i = 0; i < 32; i += 8)
        WT[(size_t)(n0 + ty + i) * 1024 + k0 + tx] = (f16)t[tx][ty + i];
}

// ---------------- big K/V GEMM: Ckv[65536][1536] = A16 @ BkvT^T + bias; stats fused ----
// m201-style 8-phase schedule: 256x256 tile, 8 waves (2x4), 8 LDS slots x 16KB
// (A0/A1/B0/B1 x tile-parity), 8 phases per 2 K-tiles, vmcnt(4) at p3/p7 only,
// XOR chunk swizzle both sides, setprio around each 16-MFMA cluster.

__global__ __launch_bounds__(512, 2) void k_gemm256(const f16* __restrict__ A,
                                                    const f16* __restrict__ Bt,
                                                    f16* __restrict__ C,
                                                    const float* __restrict__ bias1,
                                                    const float* __restrict__ bias2,
                                                    float* __restrict__ stats) {
    extern __shared__ char lds[];
    const int tid = threadIdx.x, lane = tid & 63, w = tid >> 6;
    const int wr = w >> 2, wc = w & 3;
    const int l15 = lane & 15, l4 = lane >> 4;

    // bijective XCD swizzle: 1536 = 8 * 192
    const int swz = ((int)blockIdx.x & 7) * 192 + ((int)blockIdx.x >> 3);
    const int bx = swz % 6, by = swz / 6;
    const size_t m0 = (size_t)by * 256, n0g = (size_t)bx * 256;

    // stage lane geometry: one gload covers 8 rows x 128B; lane L -> row +(L>>3),
    // LDS pos (L&7); global chunk pre-swizzled: (L&7)^(L>>3)  [pos p holds chunk p^(row&7)]
    const int srow = w * 16 + (lane >> 3);
    const int schunk = (lane & 7) ^ (lane >> 3);
    const f16* sA = A + (m0 + srow) * 1024 + schunk * 8;
    const f16* sB = Bt + (n0g + srow) * 1024 + schunk * 8;
    char* const ldsw = lds + w * 2048;

    // fragment-read constants: row stride 128B; pos = (kchunk) ^ (row&7), row&7 = l15&7
    const int p0off = ((l4 ^ (l15 & 7))) * 16;
    const int p1off = (((4 | l4) ^ (l15 & 7))) * 16;
    const char* fA = lds + wr * 16384 + l15 * 128;
    const char* fB = lds + (2 + (wc >> 1)) * 16384 + ((wc & 1) * 64 + l15) * 128;

    f32x4 acc[8][4] = {};
    f16x8 bfr[4][2];

#define STG(kt, part, isB, j)                                                      \
    gload_lds16(((isB) ? sB : sA) + ((part) * 128 + (j) * 8) * 1024 + ((kt) & 15) * 64, \
                ldsw + ((((kt) & 1) * 4 + ((isB) ? 2 : 0) + (part)) * 16384) + (j) * 1024)
#define STG2(kt, part, isB) { STG(kt, part, isB, 0); STG(kt, part, isB, 1); }

#define PHASE(PAR, MQ, VM, STAGES)                                                 \
    {                                                                              \
        if (MQ == 0) {                                                             \
            _Pragma("unroll") for (int n = 0; n < 4; n++) {                        \
                bfr[n][0] = *(const f16x8*)(fB + (PAR)*65536 + n * 2048 + p0off);  \
                bfr[n][1] = *(const f16x8*)(fB + (PAR)*65536 + n * 2048 + p1off);  \
            }                                                                      \
        }                                                                          \
        f16x8 a0k0 = *(const f16x8*)(fA + (PAR)*65536 + (MQ * 2) * 2048 + p0off);  \
        f16x8 a0k1 = *(const f16x8*)(fA + (PAR)*65536 + (MQ * 2) * 2048 + p1off);  \
        f16x8 a1k0 = *(const f16x8*)(fA + (PAR)*65536 + (MQ * 2 + 1) * 2048 + p0off); \
        f16x8 a1k1 = *(const f16x8*)(fA + (PAR)*65536 + (MQ * 2 + 1) * 2048 + p1off); \
        STAGES;                                                                    \
        if ((VM) >= 0) asm volatile("s_waitcnt vmcnt(4)" ::: "memory");            \
        __builtin_amdgcn_s_barrier();                                              \
        __builtin_amdgcn_s_setprio(1);                                             \
        _Pragma("unroll") for (int n = 0; n < 4; n++) {                            \
            acc[MQ * 2][n] = mfma16(a0k0, bfr[n][0], acc[MQ * 2][n]);              \
            acc[MQ * 2][n] = mfma16(a0k1, bfr[n][1], acc[MQ * 2][n]);              \
            acc[MQ * 2 + 1][n] = mfma16(a1k0, bfr[n][0], acc[MQ * 2 + 1][n]);      \
            acc[MQ * 2 + 1][n] = mfma16(a1k1, bfr[n][1], acc[MQ * 2 + 1][n]);      \
        }                                                                          \
        __builtin_amdgcn_s_setprio(0);                                             \
        __builtin_amdgcn_s_barrier();                                              \
    }

    // prologue: B0(0),B1(0),A0(0),A1(0),B0(1),B1(1); retire tile 0 (first 8 loads)
    STG2(0, 0, 1) STG2(0, 1, 1) STG2(0, 0, 0) STG2(0, 1, 0) STG2(1, 0, 1) STG2(1, 1, 1)
    asm volatile("s_waitcnt vmcnt(4)" ::: "memory");
    __builtin_amdgcn_s_barrier();

#pragma unroll 1
    for (int i = 0; i < 8; i++) {
        const int t1 = 2 * i + 1, t2 = 2 * i + 2, t3 = 2 * i + 3;
        PHASE(0, 0, -1, STG2(t1, 0, 0))                    // p0: stage A0(t+1)
        PHASE(0, 1, -1, STG2(t1, 1, 0); STG2(t2, 0, 1))    // p1: A1(t+1), B0(t+2)
        PHASE(0, 2, -1, STG2(t2, 1, 1))                    // p2: B1(t+2)
        PHASE(0, 3, 4, (void)0)                            // p3: vmcnt(4) -> tile t+1 ready
        PHASE(1, 0, -1, STG2(t2, 0, 0))                    // p4: A0(t+2)
        PHASE(1, 1, -1, STG2(t2, 1, 0); STG2(t3, 0, 1))    // p5: A1(t+2), B0(t+3)
        PHASE(1, 2, -1, STG2(t3, 1, 1))                    // p6: B1(t+3)
        PHASE(1, 3, 4, (void)0)                            // p7: vmcnt(4) -> tile t+2 ready
    }
#undef PHASE
#undef STG2
#undef STG

    asm volatile("s_waitcnt vmcnt(0)" ::: "memory");
    __syncthreads();

    // ---- epilogue 1: C tile (f16 + bias) via LDS for coalesced stores ----
    {
        f16* Ct = (f16*)lds;
#pragma unroll
        for (int m = 0; m < 8; m++)
#pragma unroll
            for (int n = 0; n < 4; n++) {
                const int row = wr * 128 + m * 16 + l4 * 4;
                const int col = wc * 64 + n * 16 + l15;
                const int cg = (int)n0g + col;
                const float bv = (cg < 512) ? bias1[cg] : bias2[cg - 512];
#pragma unroll
                for (int j = 0; j < 4; j++)
                    Ct[(row + j) * 256 + col] = (f16)(acc[m][n][j] + bv);
            }
        __syncthreads();
#pragma unroll
        for (int it = 0; it < 16; it++) {
            const int flat = it * 512 + tid;
            const int row = flat >> 5;
            const int ce = (flat & 31) * 8;
            *(f16x8*)(C + (m0 + row) * 1536 + n0g + ce) = *(const f16x8*)(Ct + row * 256 + ce);
        }
        __syncthreads();
    }
    // ---- epilogue 2: fused LN row partial sums -> global atomics ----
    {
        float* SP = (float*)lds;  // [256 rows][4 wc][2 comp]
        const int part = (n0g >= 512) ? 1 : 0;
#pragma unroll
        for (int half = 0; half < 2; half++) {
            float s1[4][4], s2[4][4];
#pragma unroll
            for (int m = 0; m < 4; m++)
#pragma unroll
                for (int j = 0; j < 4; j++) { s1[m][j] = 0.f; s2[m][j] = 0.f; }
#pragma unroll
            for (int m = 0; m < 4; m++) {
                const int mm = half * 4 + m;
#pragma unroll
                for (int n = 0; n < 4; n++) {
                    const int cg = (int)n0g + wc * 64 + n * 16 + l15;
                    const float bv = (cg < 512) ? bias1[cg] : bias2[cg - 512];
#pragma unroll
                    for (int j = 0; j < 4; j++) {
                        const float v = acc[mm][n][j] + bv;
                        s1[m][j] += v;
                        s2[m][j] += v * v;
                    }
                }
#pragma unroll
                for (int j = 0; j < 4; j++) {
#pragma unroll
                    for (int o = 1; o < 16; o <<= 1) {
                        s1[m][j] += __shfl_xor(s1[m][j], o);
                        s2[m][j] += __shfl_xor(s2[m][j], o);
                    }
                }
            }
            if (l15 == 0) {
#pragma unroll
                for (int m = 0; m < 4; m++)
#pragma unroll
                    for (int j = 0; j < 4; j++) {
                        const int row = wr * 128 + (half * 4 + m) * 16 + l4 * 4 + j;
                        SP[row * 8 + wc * 2 + 0] = s1[m][j];
                        SP[row * 8 + wc * 2 + 1] = s2[m][j];
                    }
            }
        }
        __syncthreads();
        {
            const int row = tid >> 1, comp = tid & 1;
            const float v = SP[row * 8 + 0 + comp] + SP[row * 8 + 2 + comp] +
                            SP[row * 8 + 4 + comp] + SP[row * 8 + 6 + comp];
            atomicAdd(stats + (m0 + row) * 4 + part * 2 + comp, v);
        }
    }
}

// finalize (sum,sumsq) -> (mu, rstd) in place
__global__ void k_statsfin(float4* __restrict__ stats) {
    const int i = blockIdx.x * 256 + threadIdx.x;
    const float4 s = stats[i];
    const float muk = s.x * (1.f / 512.f);
    const float vk = s.y * (1.f / 512.f) - muk * muk;
    const float muv = s.z * (1.f / 1024.f);
    const float vv = s.w * (1.f / 1024.f) - muv * muv;
    stats[i] = make_float4(muk, rsqrtf(vk + LN_EPS), muv, rsqrtf(vv + LN_EPS));
}

// ---------------- small GEMM (q / proj): 128x128 tile, m97-style ----------------

template <bool OUTF32>
__global__ __launch_bounds__(256, 2) void k_gemm(const f16* __restrict__ A,
                                                 const f16* __restrict__ Bt,
                                                 void* __restrict__ Cout, int Ncols, int Kd,
                                                 const float* __restrict__ bias1,
                                                 const float* __restrict__ bias2, int bsplit) {
    __shared__ f16 smem[16384];
    const int tid = threadIdx.x, lane = tid & 63, wave = tid >> 6;
    const int m0 = blockIdx.y * 128, n0 = blockIdx.x * 128;
    const size_t ldb = (size_t)Kd * 2;
    f32x4 acc[4][4] = {};

    const int rA = wave * 8 + (lane >> 3);
    const int slot = (lane & 7) * 16;
    const char* Ab = (const char*)A + (size_t)(m0 + rA) * ldb + slot;
    const char* Bb = (const char*)Bt + (size_t)(n0 + rA) * ldb + slot;
    char* lA = (char*)smem + wave * 1024;
    char* lB = (char*)smem + 16384 + wave * 1024;

    const int wm = (wave & 1) * 64, wn = (wave >> 1) * 64;

    for (int k0 = 0; k0 < Kd; k0 += 64) {
#pragma unroll
        for (int i = 0; i < 4; i++) {
            gload_lds16(Ab + (size_t)k0 * 2 + (size_t)i * 32 * ldb, lA + i * 4096);
            gload_lds16(Bb + (size_t)k0 * 2 + (size_t)i * 32 * ldb, lB + i * 4096);
        }
        __syncthreads();
#pragma unroll
        for (int kk = 0; kk < 64; kk += 32) {
            const int kb = (kk + (lane >> 4) * 8) * 2;
            f16x8 af[4], bf[4];
#pragma unroll
            for (int mi = 0; mi < 4; mi++)
                af[mi] = *(const f16x8*)((const char*)smem + (wm + mi * 16 + (lane & 15)) * 128 + kb);
#pragma unroll
            for (int ni = 0; ni < 4; ni++)
                bf[ni] = *(const f16x8*)((const char*)smem + 16384 + (wn + ni * 16 + (lane & 15)) * 128 + kb);
#pragma unroll
            for (int mi = 0; mi < 4; mi++)
#pragma unroll
                for (int ni = 0; ni < 4; ni++)
                    acc[mi][ni] = mfma16(af[mi], bf[ni], acc[mi][ni]);
        }
        __syncthreads();
    }

    if (!OUTF32) {
        f16* Ct = smem;
#pragma unroll
        for (int mi = 0; mi < 4; mi++) {
#pragma unroll
            for (int ni = 0; ni < 4; ni++) {
                const int r = wm + mi * 16 + (lane >> 4) * 4;
                const int c = wn + ni * 16 + (lane & 15);
                const int cg = n0 + c;
                const float bv = (cg < bsplit) ? bias1[cg] : bias2[cg - bsplit];
#pragma unroll
                for (int j = 0; j < 4; j++) Ct[(r + j) * 128 + c] = (f16)(acc[mi][ni][j] + bv);
            }
        }
        __syncthreads();
        f16* Cg = (f16*)Cout;
        const int r = tid >> 1, half = tid & 1;
        const f16* src = Ct + r * 128 + half * 64;
        f16* dst = Cg + (size_t)(m0 + r) * Ncols + n0 + half * 64;
#pragma unroll
        for (int i = 0; i < 8; i++) *(f16x8*)(dst + i * 8) = *(const f16x8*)(src + i * 8);
    } else {
        float* Cg = (float*)Cout;
#pragma unroll
        for (int mi = 0; mi < 4; mi++) {
#pragma unroll
            for (int ni = 0; ni < 4; ni++) {
                const int r = wm + mi * 16 + (lane >> 4) * 4;
                const int c = wn + ni * 16 + (lane & 15);
                const int cg = n0 + c;
                const float bv = (cg < bsplit) ? bias1[cg] : bias2[cg - bsplit];
#pragma unroll
                for (int j = 0; j < 4; j++)
                    Cg[(size_t)(m0 + r + j) * Ncols + cg] = acc[mi][ni][j] + bv;
            }
        }
    }
}

// ---------------- column softmax stats (k^T over tokens), slab = 64 rows ----------------

__global__ __launch_bounds__(256) void k_colstats1(const f16* __restrict__ Ckv,
                                                   const float4* __restrict__ stats,
                                                   const float* __restrict__ kg,
                                                   const float* __restrict__ kb,
                                                   float* __restrict__ pm, float* __restrict__ ps) {
    const int b = blockIdx.y, slab = blockIdx.x, t = threadIdx.x;
    const int c0 = t * 2;
    const float g0 = kg[c0], g1 = kg[c0 + 1], e0 = kb[c0], e1 = kb[c0 + 1];
    const size_t r0 = (size_t)b * 8192 + slab * 64;
    float m0 = -1e30f, m1 = -1e30f;
    for (int r = 0; r < 64; r++) {
        const float4 st = stats[r0 + r];
        union { unsigned u; f16 h[2]; } w;
        w.u = *(const unsigned*)(Ckv + (r0 + r) * 1536 + c0);
        const float z0 = ((float)w.h[0] - st.x) * st.y * g0 + e0;
        const float z1 = ((float)w.h[1] - st.x) * st.y * g1 + e1;
        m0 = fmaxf(m0, z0);
        m1 = fmaxf(m1, z1);
    }
    float s0 = 0.f, s1 = 0.f;
    for (int r = 0; r < 64; r++) {
        const float4 st = stats[r0 + r];
        union { unsigned u; f16 h[2]; } w;
        w.u = *(const unsigned*)(Ckv + (r0 + r) * 1536 + c0);
        const float z0 = ((float)w.h[0] - st.x) * st.y * g0 + e0;
        const float z1 = ((float)w.h[1] - st.x) * st.y * g1 + e1;
        s0 += __expf(z0 - m0);
        s1 += __expf(z1 - m1);
    }
    const int o = (b * 128 + slab) * 512 + c0;
    pm[o] = m0; pm[o + 1] = m1;
    ps[o] = s0; ps[o + 1] = s1;
}

__global__ void k_colstats2(const float* __restrict__ pm, const float* __restrict__ ps,
                            float* __restrict__ Mx, float* __restrict__ invZ) {
    const int idx = blockIdx.x * 256 + threadIdx.x;  // 0..4095
    const int b = idx >> 9, c = idx & 511;
    float M = -1e30f;
    for (int s = 0; s < 128; s++) M = fmaxf(M, pm[(b * 128 + s) * 512 + c]);
    float S = 0.f;
    for (int s = 0; s < 128; s++) S += ps[(b * 128 + s) * 512 + c] * __expf(pm[(b * 128 + s) * 512 + c] - M);
    Mx[idx] = M;
    invZ[idx] = 1.0f / S;
}

// ---------------- kv einsum partials over token splits ----------------

__global__ __launch_bounds__(256, 2) void k_kv(const f16* __restrict__ Ckv,
                                               const float4* __restrict__ stats,
                                               const float* __restrict__ kg,
                                               const float* __restrict__ kbe,
                                               const float* __restrict__ vg,
                                               const float* __restrict__ vbe,
                                               const float* __restrict__ Mx,
                                               float* __restrict__ kvpart) {
    __shared__ f16 As[64 * 64];
    __shared__ f16 Vs[128 * 64];
    __shared__ float cgk[64], cbk[64], cmx[64], cgv[128], cbv[128];
    const int split = blockIdx.x, bh = blockIdx.y;
    const int b = bh >> 3, h = bh & 7;
    const int tid = threadIdx.x, lane = tid & 63, wave = tid >> 6;
    if (tid < 64) {
        cgk[tid] = kg[h * 64 + tid];
        cbk[tid] = kbe[h * 64 + tid];
        cmx[tid] = Mx[b * 512 + h * 64 + tid];
    }
    if (tid < 128) {
        cgv[tid] = vg[h * 128 + tid];
        cbv[tid] = vbe[h * 128 + tid];
    }
    __syncthreads();
    f32x4 acc[8] = {};
    const size_t base = (size_t)b * 8192 + split * 1024;
    for (int t0 = 0; t0 < 1024; t0 += 64) {
        {
            const int g = tid & 7, p = tid >> 3;
            const size_t row = base + t0 + 2 * p;
            const f16x8 x0 = *(const f16x8*)(Ckv + row * 1536 + h * 64 + g * 8);
            const f16x8 x1 = *(const f16x8*)(Ckv + (row + 1) * 1536 + h * 64 + g * 8);
            const float4 s0 = stats[row], s1 = stats[row + 1];
#pragma unroll
            for (int j = 0; j < 8; j++) {
                const int c = g * 8 + j;
                const float z0 = ((float)x0[j] - s0.x) * s0.y * cgk[c] + cbk[c] - cmx[c];
                const float z1 = ((float)x1[j] - s1.x) * s1.y * cgk[c] + cbk[c] - cmx[c];
                union { unsigned u; f16 h2[2]; } pk;
                pk.h2[0] = (f16)__expf(z0);
                pk.h2[1] = (f16)__expf(z1);
                *(unsigned*)((char*)As + c * 128 + 4 * p) = pk.u;
            }
        }
#pragma unroll
        for (int sub = 0; sub < 2; sub++) {
            const int idx = tid + sub * 256;
            const int g = idx & 15, p = idx >> 4;
            const size_t row = base + t0 + 2 * p;
            const f16x8 x0 = *(const f16x8*)(Ckv + row * 1536 + 512 + h * 128 + g * 8);
            const f16x8 x1 = *(const f16x8*)(Ckv + (row + 1) * 1536 + 512 + h * 128 + g * 8);
            const float4 s0 = stats[row], s1 = stats[row + 1];
#pragma unroll
            for (int j = 0; j < 8; j++) {
                const int d = g * 8 + j;
                const float z0 = ((float)x0[j] - s0.z) * s0.w * cgv[d] + cbv[d];
                const float z1 = ((float)x1[j] - s1.z) * s1.w * cgv[d] + cbv[d];
                union { unsigned u; f16 h2[2]; } pk;
                pk.h2[0] = (f16)z0;
                pk.h2[1] = (f16)z1;
                *(unsigned*)((char*)Vs + d * 128 + 4 * p) = pk.u;
            }
        }
        __syncthreads();
#pragma unroll
        for (int kk = 0; kk < 64; kk += 32) {
            const int kb2 = (kk + (lane >> 4) * 8) * 2;
            const f16x8 af = *(const f16x8*)((const char*)As + (wave * 16 + (lane & 15)) * 128 + kb2);
#pragma unroll
            for (int ni = 0; ni < 8; ni++) {
                const f16x8 bf = *(const f16x8*)((const char*)Vs + (ni * 16 + (lane & 15)) * 128 + kb2);
                acc[ni] = mfma16(af, bf, acc[ni]);
            }
        }
        __syncthreads();
    }
    float* out = kvpart + ((size_t)split * 64 + bh) * 8192;
    const int l = wave * 16 + (lane >> 4) * 4;
#pragma unroll
    for (int ni = 0; ni < 8; ni++) {
        const int d = ni * 16 + (lane & 15);
#pragma unroll
        for (int j = 0; j < 4; j++) out[(l + j) * 128 + d] = acc[ni][j];
    }
}

__global__ void k_kvreduce(const float* __restrict__ kvpart, const float* __restrict__ invZ,
                           f16* __restrict__ kvT) {
    const int idx = blockIdx.x * 256 + threadIdx.x;
    const int d = idx & 127, l = (idx >> 7) & 63, bh = idx >> 13;
    const int b = bh >> 3, h = bh & 7;
    float s = 0.f;
#pragma unroll
    for (int sp = 0; sp < 8; sp++) s += kvpart[((size_t)sp * 64 + bh) * 8192 + l * 128 + d];
    s *= invZ[b * 512 + h * 64 + l];
    kvT[((size_t)bh * 128 + d) * 64 + l] = (f16)s;
}

// ---------------- q: LN + per-head softmax ----------------

__global__ __launch_bounds__(512) void k_qsm(const f16* __restrict__ qlin,
                                             const float* __restrict__ qg,
                                             const float* __restrict__ qbeta,
                                             f16* __restrict__ qsm) {
    const int row = blockIdx.x, t = threadIdx.x;
    const float x = (float)qlin[(size_t)row * 512 + t];
    float s = x, s2 = x * x;
#pragma unroll
    for (int off = 32; off; off >>= 1) {
        s += __shfl_xor(s, off);
        s2 += __shfl_xor(s2, off);
    }
    __shared__ float rs[16];
    const int wave = t >> 6, lane = t & 63;
    if (lane == 0) {
        rs[wave] = s;
        rs[8 + wave] = s2;
    }
    __syncthreads();
    float S = 0.f, S2 = 0.f;
#pragma unroll
    for (int w = 0; w < 8; w++) {
        S += rs[w];
        S2 += rs[8 + w];
    }
    const float mu = S * (1.0f / 512.0f);
    const float var = S2 * (1.0f / 512.0f) - mu * mu;
    const float z = (x - mu) * rsqrtf(var + LN_EPS) * qg[t] + qbeta[t];
    float m = z;
#pragma unroll
    for (int off = 32; off; off >>= 1) m = fmaxf(m, __shfl_xor(m, off));
    const float e = __expf(z - m);
    float se = e;
#pragma unroll
    for (int off = 32; off; off >>= 1) se += __shfl_xor(se, off);
    qsm[(size_t)row * 512 + t] = (f16)(e / se);
}

// ---------------- out_mid = qsm @ kvT ----------------

__global__ __launch_bounds__(256) void k_qkv(const f16* __restrict__ qsm,
                                             const f16* __restrict__ kvT,
                                             f16* __restrict__ omid) {
    const int ms = blockIdx.x, bh = blockIdx.y;
    const int b = bh >> 3, h = bh & 7;
    const int tid = threadIdx.x, lane = tid & 63, wave = tid >> 6;
    const int mr = ms * 64 + wave * 16;
    f32x4 acc[8] = {};
    const f16* Ab = qsm + (size_t)(b * 256 + mr + (lane & 15)) * 512 + h * 64;
    const f16* Bb = kvT + (size_t)bh * 8192;
#pragma unroll
    for (int kk = 0; kk < 64; kk += 32) {
        const int k = kk + (lane >> 4) * 8;
        const f16x8 af = *(const f16x8*)(Ab + k);
#pragma unroll
        for (int ni = 0; ni < 8; ni++) {
            const f16x8 bf = *(const f16x8*)(Bb + (ni * 16 + (lane & 15)) * 64 + k);
            acc[ni] = mfma16(af, bf, acc[ni]);
        }
    }
    const int r = b * 256 + mr + (lane >> 4) * 4;
#pragma unroll
    for (int ni = 0; ni < 8; ni++) {
        const int d = h * 128 + ni * 16 + (lane & 15);
#pragma unroll
        for (int j = 0; j < 4; j++) omid[(size_t)(r + j) * 1024 + d] = (f16)acc[ni][j];
    }
}

// ---------------- launch ----------------

extern "C" void kernel_launch(void* const* d_in, const int* in_sizes, int n_in,
                              void* d_out, int out_size, void* d_ws, size_t ws_size,
                              hipStream_t stream) {
    const float* input  = (const float*)d_in[0];
    const float* query  = (const float*)d_in[1];
    const float* q_w    = (const float*)d_in[2];
    const float* q_b    = (const float*)d_in[3];
    const float* q_g    = (const float*)d_in[4];
    const float* q_beta = (const float*)d_in[5];
    const float* k_w    = (const float*)d_in[6];
    const float* k_b    = (const float*)d_in[7];
    const float* k_g    = (const float*)d_in[8];
    const float* k_beta = (const float*)d_in[9];
    const float* v_w    = (const float*)d_in[10];
    const float* v_b    = (const float*)d_in[11];
    const float* v_g    = (const float*)d_in[12];
    const float* v_beta = (const float*)d_in[13];
    const float* proj_w = (const float*)d_in[14];
    const float* proj_b = (const float*)d_in[15];

    char* ws = (char*)d_ws;
    size_t off = 0;
    auto alloc = [&](size_t bytes) {
        char* p = ws + off;
        off += (bytes + 255) & ~(size_t)255;
        return p;
    };
    f16*   A16    = (f16*)alloc((size_t)67108864 * 2);
    f16*   Q16    = (f16*)alloc((size_t)2097152 * 2);
    f16*   BkvT   = (f16*)alloc((size_t)1536 * 1024 * 2);
    f16*   qwT    = (f16*)alloc((size_t)512 * 1024 * 2);
    f16*   pwT    = (f16*)alloc((size_t)1024 * 1024 * 2);
    f16*   Ckv    = (f16*)alloc((size_t)65536 * 1536 * 2);
    float* stats  = (float*)alloc((size_t)65536 * 16);
    float* pm     = (float*)alloc((size_t)8 * 128 * 512 * 4);
    float* ps     = (float*)alloc((size_t)8 * 128 * 512 * 4);
    float* Mx     = (float*)alloc((size_t)8 * 512 * 4);
    float* invZ   = (float*)alloc((size_t)8 * 512 * 4);
    f16*   qlin   = (f16*)alloc((size_t)2048 * 512 * 2);
    f16*   qsm    = (f16*)alloc((size_t)2048 * 512 * 2);
    float* kvpart = (float*)alloc((size_t)8 * 64 * 64 * 128 * 4);
    f16*   kvT    = (f16*)alloc((size_t)64 * 128 * 64 * 2);
    f16*   omid   = (f16*)alloc((size_t)2048 * 1024 * 2);
    (void)ws_size; (void)in_sizes; (void)n_in; (void)out_size;

    hipFuncSetAttribute(reinterpret_cast<const void*>(k_gemm256),
                        hipFuncAttributeMaxDynamicSharedMemorySize, 131072);

    // 0) zero the fused-stats accumulator
    hipMemsetAsync(stats, 0, (size_t)65536 * 16, stream);

    // 1) converts + weight transposes
    k_cvt_dual<<<2048, 256, 0, stream>>>((const float4*)input, (const float4*)query,
                                         (f16x4*)A16, (f16x4*)Q16, 16777216, 17301504);
    k_transpose_all<<<dim3(96, 32), 256, 0, stream>>>(k_w, v_w, q_w, proj_w, BkvT, qwT, pwT);

    // 2) fused K/V projection GEMM (8-phase pipelined) + LN stats accumulation
    k_gemm256<<<1536, 512, 131072, stream>>>(A16, BkvT, Ckv, k_b, v_b, stats);
    k_statsfin<<<256, 256, 0, stream>>>((float4*)stats);

    // 3) column softmax stats for k^T
    k_colstats1<<<dim3(128, 8), 256, 0, stream>>>(Ckv, (const float4*)stats, k_g, k_beta, pm, ps);
    k_colstats2<<<16, 256, 0, stream>>>(pm, ps, Mx, invZ);

    // 4) kv einsum + reduce
    k_kv<<<dim3(8, 64), 256, 0, stream>>>(Ckv, (const float4*)stats, k_g, k_beta, v_g, v_beta, Mx, kvpart);
    k_kvreduce<<<2048, 256, 0, stream>>>(kvpart, invZ, kvT);

    // 5) q path
    k_gemm<false><<<dim3(4, 16), 256, 0, stream>>>(Q16, qwT, qlin, 512, 1024, q_b, q_b, 512);
    k_qsm<<<2048, 512, 0, stream>>>(qlin, q_g, q_beta, qsm);
    k_qkv<<<dim3(4, 64), 256, 0, stream>>>(qsm, kvT, omid);
    k_gemm<true><<<dim3(8, 16), 256, 0, stream>>>(omid, pwT, d_out, 1024, 1024, proj_b, proj_b, 2048);
}